// Round 1
// baseline (2474.611 us; speedup 1.0000x reference)
//
#include <hip/hip_runtime.h>
#include <cmath>

#define L_LEVELS 16
#define F_FEAT 2
#define T_SIZE 524288u
#define T_MASK (T_SIZE - 1u)
#define P1 2654435761u
#define P2 805459861u

struct ResArr { int r[L_LEVELS]; };

// One thread per (point, level). lanes [0..15] of each 16-thread group share a
// point; level = tid & 15. Wave writes 512B contiguous (coalesced float2).
__global__ __launch_bounds__(256) void hash_enc_kernel(
    const float* __restrict__ x,
    const float* __restrict__ emb,
    float* __restrict__ out,
    ResArr res, int npts)
{
    __shared__ float xsh[48];  // 16 points * 3 coords staged once per block
    const int tid = threadIdx.x;
    const int blockPointBase = blockIdx.x * 16;
    if (tid < 48) xsh[tid] = x[(size_t)blockPointBase * 3 + tid];
    __syncthreads();

    const int lp    = tid >> 4;   // local point 0..15
    const int level = tid & 15;
    const int p     = blockPointBase + lp;
    if (p >= npts) return;

    // 16 lanes read same address -> LDS broadcast, conflict-free
    const float px = xsh[lp * 3 + 0];
    const float py = xsh[lp * 3 + 1];
    const float pz = xsh[lp * 3 + 2];

    const float rf = (float)res.r[level];
    // must be single fp32 multiplies to bit-match reference rounding
    const float sx = px * rf, sy = py * rf, sz = pz * rf;
    const int ix = (int)sx, iy = (int)sy, iz = (int)sz;  // x>=0 -> trunc==floor
    const float fx = sx - (float)ix;
    const float fy = sy - (float)iy;
    const float fz = sz - (float)iz;

    // hash: low 19 bits only -> uint32 arithmetic is exact vs reference int64
    const unsigned hx0 = (unsigned)ix;
    const unsigned hx1 = hx0 + 1u;
    const unsigned hy0 = (unsigned)iy * P1;
    const unsigned hy1 = hy0 + P1;
    const unsigned hz0 = (unsigned)iz * P2;
    const unsigned hz1 = hz0 + P2;

    // OFFSETS order: index bit2 = x-offset, bit1 = y-offset, bit0 = z-offset
    const unsigned h0 = (hx0 ^ hy0 ^ hz0) & T_MASK;
    const unsigned h1 = (hx0 ^ hy0 ^ hz1) & T_MASK;
    const unsigned h2 = (hx0 ^ hy1 ^ hz0) & T_MASK;
    const unsigned h3 = (hx0 ^ hy1 ^ hz1) & T_MASK;
    const unsigned h4 = (hx1 ^ hy0 ^ hz0) & T_MASK;
    const unsigned h5 = (hx1 ^ hy0 ^ hz1) & T_MASK;
    const unsigned h6 = (hx1 ^ hy1 ^ hz0) & T_MASK;
    const unsigned h7 = (hx1 ^ hy1 ^ hz1) & T_MASK;

    const float2* __restrict__ E = (const float2*)emb + (size_t)level * T_SIZE;
    const float2 c0v = E[h0];
    const float2 c1v = E[h1];
    const float2 c2v = E[h2];
    const float2 c3v = E[h3];
    const float2 c4v = E[h4];
    const float2 c5v = E[h5];
    const float2 c6v = E[h6];
    const float2 c7v = E[h7];

    const float gx = 1.0f - fx, gy = 1.0f - fy, gz = 1.0f - fz;
    // exact reference association: a*(1-f) + b*f
    const float c00x = c0v.x * gx + c4v.x * fx;
    const float c00y = c0v.y * gx + c4v.y * fx;
    const float c01x = c1v.x * gx + c5v.x * fx;
    const float c01y = c1v.y * gx + c5v.y * fx;
    const float c10x = c2v.x * gx + c6v.x * fx;
    const float c10y = c2v.y * gx + c6v.y * fx;
    const float c11x = c3v.x * gx + c7v.x * fx;
    const float c11y = c3v.y * gx + c7v.y * fx;

    const float a0x = c00x * gy + c10x * fy;
    const float a0y = c00y * gy + c10y * fy;
    const float a1x = c01x * gy + c11x * fy;
    const float a1y = c01y * gy + c11y * fy;

    const float ox = a0x * gz + a1x * fz;
    const float oy = a0y * gz + a1y * fz;

    // out row = 32 floats = 16 float2; wave writes 512B contiguous
    float2* __restrict__ O = (float2*)out;
    O[(size_t)p * 16 + level] = make_float2(ox, oy);
}

extern "C" void kernel_launch(void* const* d_in, const int* in_sizes, int n_in,
                              void* d_out, int out_size, void* d_ws, size_t ws_size,
                              hipStream_t stream) {
    const float* x   = (const float*)d_in[0];
    const float* emb = (const float*)d_in[1];
    float* out       = (float*)d_out;

    // Replicate Python: b = exp((log(2048)-log(16))/15); res_i = floor(16 * b**i)
    // Same libm (exp/log/pow/floor in double) -> bit-identical resolutions.
    ResArr res;
    const double b = exp((log(2048.0) - log(16.0)) / 15.0);
    for (int i = 0; i < L_LEVELS; ++i)
        res.r[i] = (int)floor(16.0 * pow(b, (double)i));

    const int npts = in_sizes[0] / 3;
    const int blocks = (npts + 15) / 16;
    hipLaunchKernelGGL(hash_enc_kernel, dim3(blocks), dim3(256), 0, stream,
                       x, emb, out, res, npts);
}

// Round 2
// 1292.735 us; speedup vs baseline: 1.9142x; 1.9142x over previous
//
#include <hip/hip_runtime.h>
#include <cmath>

#define L_LEVELS 16
#define T_SIZE 524288u
#define T_MASK (T_SIZE - 1u)
#define P1 2654435761u
#define P2 805459861u

struct ResArr { int r[L_LEVELS]; };

// ---------------------------------------------------------------------------
// K1: one thread per (point, level). grid = (npts/256, 16 levels), x-fastest
// dispatch order => chip processes levels ~sequentially => each XCD's 4MB L2
// holds exactly the current level's 4MB table => gathers hit L2.
// Writes level-major ws[level][point] (wave writes 512B contiguous).
// ---------------------------------------------------------------------------
__global__ __launch_bounds__(256) void enc_level_kernel(
    const float* __restrict__ x,
    const float* __restrict__ emb,
    float2* __restrict__ ws,
    ResArr res, int npts)
{
    __shared__ float xsh[768];           // 256 points * 3 coords
    const int tid   = threadIdx.x;
    const int level = blockIdx.y;
    const int pbase = blockIdx.x * 256;

    // stage x: 192 float4 loads cover 768 floats, fully coalesced
    if (pbase + 256 <= npts) {
        if (tid < 192)
            ((float4*)xsh)[tid] = ((const float4*)(x + (size_t)pbase * 3))[tid];
    } else {
        const int nfl = npts * 3 - pbase * 3;
        for (int i = tid; i < nfl; i += 256) xsh[i] = x[(size_t)pbase * 3 + i];
    }
    __syncthreads();

    const int p = pbase + tid;
    if (p >= npts) return;

    // lds[3t+c]: 3t mod 32 covers all banks, 2 lanes/bank -> conflict-free
    const float px = xsh[tid * 3 + 0];
    const float py = xsh[tid * 3 + 1];
    const float pz = xsh[tid * 3 + 2];

    const float rf = (float)res.r[level];
    // single fp32 multiplies to bit-match reference rounding
    const float sx = px * rf, sy = py * rf, sz = pz * rf;
    const int ix = (int)sx, iy = (int)sy, iz = (int)sz;  // x>=0 -> trunc==floor
    const float fx = sx - (float)ix;
    const float fy = sy - (float)iy;
    const float fz = sz - (float)iz;

    // hash keeps only low 19 bits -> uint32 arithmetic exact vs int64 reference
    const unsigned hx0 = (unsigned)ix,      hx1 = hx0 + 1u;
    const unsigned hy0 = (unsigned)iy * P1, hy1 = hy0 + P1;
    const unsigned hz0 = (unsigned)iz * P2, hz1 = hz0 + P2;

    const unsigned h0 = (hx0 ^ hy0 ^ hz0) & T_MASK;
    const unsigned h1 = (hx0 ^ hy0 ^ hz1) & T_MASK;
    const unsigned h2 = (hx0 ^ hy1 ^ hz0) & T_MASK;
    const unsigned h3 = (hx0 ^ hy1 ^ hz1) & T_MASK;
    const unsigned h4 = (hx1 ^ hy0 ^ hz0) & T_MASK;
    const unsigned h5 = (hx1 ^ hy0 ^ hz1) & T_MASK;
    const unsigned h6 = (hx1 ^ hy1 ^ hz0) & T_MASK;
    const unsigned h7 = (hx1 ^ hy1 ^ hz1) & T_MASK;

    const float2* __restrict__ E = (const float2*)emb + (size_t)level * T_SIZE;
    const float2 c0v = E[h0];
    const float2 c1v = E[h1];
    const float2 c2v = E[h2];
    const float2 c3v = E[h3];
    const float2 c4v = E[h4];
    const float2 c5v = E[h5];
    const float2 c6v = E[h6];
    const float2 c7v = E[h7];

    const float gx = 1.0f - fx, gy = 1.0f - fy, gz = 1.0f - fz;
    // exact reference association: a*(1-f) + b*f
    const float c00x = c0v.x * gx + c4v.x * fx;
    const float c00y = c0v.y * gx + c4v.y * fx;
    const float c01x = c1v.x * gx + c5v.x * fx;
    const float c01y = c1v.y * gx + c5v.y * fx;
    const float c10x = c2v.x * gx + c6v.x * fx;
    const float c10y = c2v.y * gx + c6v.y * fx;
    const float c11x = c3v.x * gx + c7v.x * fx;
    const float c11y = c3v.y * gx + c7v.y * fx;

    const float a0x = c00x * gy + c10x * fy;
    const float a0y = c00y * gy + c10y * fy;
    const float a1x = c01x * gy + c11x * fy;
    const float a1y = c01y * gy + c11y * fy;

    ws[(size_t)level * npts + p] =
        make_float2(a0x * gz + a1x * fz, a0y * gz + a1y * fz);
}

// ---------------------------------------------------------------------------
// K2: transpose ws[level][point] (float2) -> out[point][level] (float2).
// Thread handles one out-float4 j: point q=j>>3, level pair (2k,2k+1), k=j&7.
// Stores: lane-consecutive float4 -> perfectly coalesced.
// Loads: per instruction, the 8 lanes sharing k read 8 consecutive float2
// = one fully-utilized 64B transaction per level-row.
// ---------------------------------------------------------------------------
__global__ __launch_bounds__(256) void transpose_kernel(
    const float2* __restrict__ ws, float4* __restrict__ out4, int npts)
{
    const size_t total = (size_t)npts * 8;  // out float4 count
    size_t j = (size_t)blockIdx.x * 256 + threadIdx.x;
    const size_t stride = (size_t)gridDim.x * 256;
    for (; j < total; j += stride) {
        const size_t q = j >> 3;
        const int    k = (int)(j & 7);
        const float2 a = ws[(size_t)(2 * k)     * npts + q];
        const float2 b = ws[(size_t)(2 * k + 1) * npts + q];
        out4[j] = make_float4(a.x, a.y, b.x, b.y);
    }
}

// ---------------------------------------------------------------------------
// Fallback (round-1 kernel): used only if ws_size is too small for the
// 256MB level-major intermediate. One thread per (point, level), 16 lanes
// = 16 levels of one point, coalesced float2 output.
// ---------------------------------------------------------------------------
__global__ __launch_bounds__(256) void hash_enc_fallback(
    const float* __restrict__ x,
    const float* __restrict__ emb,
    float* __restrict__ out,
    ResArr res, int npts)
{
    __shared__ float xsh[48];
    const int tid = threadIdx.x;
    const int blockPointBase = blockIdx.x * 16;
    if (tid < 48) xsh[tid] = x[(size_t)blockPointBase * 3 + tid];
    __syncthreads();

    const int lp    = tid >> 4;
    const int level = tid & 15;
    const int p     = blockPointBase + lp;
    if (p >= npts) return;

    const float px = xsh[lp * 3 + 0];
    const float py = xsh[lp * 3 + 1];
    const float pz = xsh[lp * 3 + 2];

    const float rf = (float)res.r[level];
    const float sx = px * rf, sy = py * rf, sz = pz * rf;
    const int ix = (int)sx, iy = (int)sy, iz = (int)sz;
    const float fx = sx - (float)ix;
    const float fy = sy - (float)iy;
    const float fz = sz - (float)iz;

    const unsigned hx0 = (unsigned)ix,      hx1 = hx0 + 1u;
    const unsigned hy0 = (unsigned)iy * P1, hy1 = hy0 + P1;
    const unsigned hz0 = (unsigned)iz * P2, hz1 = hz0 + P2;

    const unsigned h0 = (hx0 ^ hy0 ^ hz0) & T_MASK;
    const unsigned h1 = (hx0 ^ hy0 ^ hz1) & T_MASK;
    const unsigned h2 = (hx0 ^ hy1 ^ hz0) & T_MASK;
    const unsigned h3 = (hx0 ^ hy1 ^ hz1) & T_MASK;
    const unsigned h4 = (hx1 ^ hy0 ^ hz0) & T_MASK;
    const unsigned h5 = (hx1 ^ hy0 ^ hz1) & T_MASK;
    const unsigned h6 = (hx1 ^ hy1 ^ hz0) & T_MASK;
    const unsigned h7 = (hx1 ^ hy1 ^ hz1) & T_MASK;

    const float2* __restrict__ E = (const float2*)emb + (size_t)level * T_SIZE;
    const float2 c0v = E[h0];
    const float2 c1v = E[h1];
    const float2 c2v = E[h2];
    const float2 c3v = E[h3];
    const float2 c4v = E[h4];
    const float2 c5v = E[h5];
    const float2 c6v = E[h6];
    const float2 c7v = E[h7];

    const float gx = 1.0f - fx, gy = 1.0f - fy, gz = 1.0f - fz;
    const float c00x = c0v.x * gx + c4v.x * fx;
    const float c00y = c0v.y * gx + c4v.y * fx;
    const float c01x = c1v.x * gx + c5v.x * fx;
    const float c01y = c1v.y * gx + c5v.y * fx;
    const float c10x = c2v.x * gx + c6v.x * fx;
    const float c10y = c2v.y * gx + c6v.y * fx;
    const float c11x = c3v.x * gx + c7v.x * fx;
    const float c11y = c3v.y * gx + c7v.y * fx;

    const float a0x = c00x * gy + c10x * fy;
    const float a0y = c00y * gy + c10y * fy;
    const float a1x = c01x * gy + c11x * fy;
    const float a1y = c01y * gy + c11y * fy;

    ((float2*)out)[(size_t)p * 16 + level] =
        make_float2(a0x * gz + a1x * fz, a0y * gz + a1y * fz);
}

extern "C" void kernel_launch(void* const* d_in, const int* in_sizes, int n_in,
                              void* d_out, int out_size, void* d_ws, size_t ws_size,
                              hipStream_t stream) {
    const float* x   = (const float*)d_in[0];
    const float* emb = (const float*)d_in[1];

    // Replicate Python: b = exp((log(2048)-log(16))/15); res_i = floor(16*b**i)
    ResArr res;
    const double b = exp((log(2048.0) - log(16.0)) / 15.0);
    for (int i = 0; i < L_LEVELS; ++i)
        res.r[i] = (int)floor(16.0 * pow(b, (double)i));

    const int npts = in_sizes[0] / 3;
    const size_t ws_needed = (size_t)npts * L_LEVELS * sizeof(float2);

    if (ws_size >= ws_needed) {
        float2* ws = (float2*)d_ws;
        const int pblocks = (npts + 255) / 256;
        hipLaunchKernelGGL(enc_level_kernel, dim3(pblocks, L_LEVELS), dim3(256),
                           0, stream, x, emb, ws, res, npts);
        const size_t total4 = (size_t)npts * 8;
        const int tblocks = (int)((total4 / 4 + 255) / 256);  // 4 float4/thread
        hipLaunchKernelGGL(transpose_kernel, dim3(tblocks), dim3(256),
                           0, stream, ws, (float4*)d_out, npts);
    } else {
        const int blocks = (npts + 15) / 16;
        hipLaunchKernelGGL(hash_enc_fallback, dim3(blocks), dim3(256),
                           0, stream, x, emb, (float*)d_out, res, npts);
    }
}